// Round 7
// baseline (109.301 us; speedup 1.0000x reference)
//
#include <hip/hip_runtime.h>

#define N 1024
#define D 256

// ---------------- prep ----------------
// 128 blocks x 8 rows, LDS-staged: coalesced float4 global loads, padded-LDS
// transpose, coalesced 8B stores. Output msT4[g][i] = (mu_2g, sig_2g,
// mu_2g+1, sig_2g+1) for column i (transposed layout).
#define RI 8
#define LDW 260

__global__ __launch_bounds__(256) void prep3(
    const float* __restrict__ muX, const float* __restrict__ ls,
    float2* __restrict__ msT2) {
  const int i0 = blockIdx.x * RI;
  const int t = threadIdx.x;
  __shared__ float smu[RI][LDW];
  __shared__ float ssg[RI][LDW];
  __shared__ float sred[RI][32];
  __shared__ float rden[RI];
  const float4* mu4 = (const float4*)(muX + (size_t)i0 * D);
  const float4* ls4 = (const float4*)(ls + (size_t)i0 * D);
#pragma unroll
  for (int u = 0; u < 2; ++u) {
    const int idx = u * 256 + t;
    const int row = idx >> 6, c4 = idx & 63;
    const float4 v = mu4[idx];
    *(float4*)&smu[row][c4 * 4] = v;
    const float4 e = ls4[idx];
    float4 x;
    x.x = __expf(e.x) + 5e-11f; x.y = __expf(e.y) + 5e-11f;  // eps folded
    x.z = __expf(e.z) + 5e-11f; x.w = __expf(e.w) + 5e-11f;
    *(float4*)&ssg[row][c4 * 4] = x;
  }
  __syncthreads();
  {
    const int r = t >> 5, q = t & 31;
    float s = 0.f;
#pragma unroll
    for (int k = 0; k < 8; ++k) {
      const float v = smu[r][q + 32 * k];
      s = fmaf(v, v, s);
    }
    sred[r][q] = s;
  }
  __syncthreads();
  if (t < RI) {
    float tot = 0.f;
    for (int u = 0; u < 32; ++u) tot += sred[t][u];
    rden[t] = 1.0f / fmaxf(sqrtf(tot), 1e-12f);  // F.normalize eps
  }
  __syncthreads();
#pragma unroll
  for (int pass = 0; pass < 8; ++pass) {
    const int f = pass * 256 + t;
    const int b = f & 1, il = (f >> 1) & 7, g = f >> 4;
    const int d = 2 * g + b;
    msT2[((size_t)g * N + i0 + il) * 2 + b] =
        make_float2(smu[il][d] * rden[il], ssg[il][d]);
  }
}

// ---------------- pair ----------------
// 16x16 triangular tiles, 2080 blocks x 2 waves (4.06 waves/SIMD).
// Lane layout: jj = lane&15 (16 DISTINCT j per wave), rr = lane>>4 (4 row
// groups), 2 rows/lane -> wave covers 8 rows x 16 cols. Duplicate j-addresses
// across the 4 row-groups are merged by the TA: j-bytes/wave-iter = 256B vs
// R5's 2KB — kills the L1-BW wall (590MB -> ~170MB total) that capped
// per-wave duty at ~25%. Mirror writes via padded-LDS transpose: every
// output store is a full 64B line (R5/R6's 8B scattered mirrors caused RFO
// fetches + write amplification: FETCH 9.3MB, WRITE 14.9MB).
__global__ __launch_bounds__(128) void pair_kernel(
    const float4* __restrict__ msT4, float* __restrict__ out) {
  const int l = blockIdx.x;
  int b = (int)((sqrtf(8.f * (float)l + 1.f) - 1.f) * 0.5f);
  while (b * (b + 1) / 2 > l) --b;
  while ((b + 1) * (b + 2) / 2 <= l) ++b;
  const int bi = l - b * (b + 1) / 2;  // row tile (<= bj)
  const int bj = b;                    // col tile
  const int i0 = bi * 16, j0 = bj * 16;

  const int t = threadIdx.x;
  const int w = t >> 6;            // wave 0/1 -> rows 0..7 / 8..15
  const int lane = t & 63;
  const int jj = lane & 15;        // distinct column within tile
  const int rr = lane >> 4;        // row group
  const int r0 = w * 8 + rr * 2;   // first of this lane's two rows

  const float4* __restrict__ pj = msT4 + (j0 + jj);
  const float4* __restrict__ pi = msT4 + (i0 + r0);

  float acc[2] = {0.f, 0.f};
  float p[2] = {1.f, 1.f};
  int ea[2] = {0, 0};

#pragma unroll 4
  for (int g = 0; g < D / 2; ++g) {
    const float4 jv = pj[(size_t)g * N];
#pragma unroll
    for (int k = 0; k < 2; ++k) {
      const float4 iv = pi[(size_t)g * N + k];
      {
        const float sv = iv.y + jv.y;
        const float t0 = iv.x - jv.x;
        acc[k] = fmaf(t0 * t0, __builtin_amdgcn_rcpf(sv), acc[k]);
        p[k] *= sv;
      }
      {
        const float sv = iv.w + jv.w;
        const float t0 = iv.z - jv.z;
        acc[k] = fmaf(t0 * t0, __builtin_amdgcn_rcpf(sv), acc[k]);
        p[k] *= sv;
      }
    }
    if (g & 1) {  // renorm every 4 d's: product exponent stays in range
#pragma unroll
      for (int k = 0; k < 2; ++k) {
        const int bb = __float_as_int(p[k]);
        ea[k] += bb >> 23;
        p[k] = __int_as_float((bb & 0x007fffff) | 0x3f800000);
      }
    }
  }

  constexpr float LN2 = 0.6931471805599453f;
  float v[2];
#pragma unroll
  for (int k = 0; k < 2; ++k) {
    const float lg2 = (float)(ea[k] - 127 * (D / 4)) + __log2f(p[k]);
    v[k] = -(acc[k] + LN2 * lg2);
  }

  __shared__ float tile[16][17];
  const bool diag = (bi == bj);

  if (!diag) {
    // direct (upper): rows i0+r0+k, col j0+jj — 64B runs per 16 lanes
#pragma unroll
    for (int k = 0; k < 2; ++k)
      out[(size_t)(i0 + r0 + k) * N + (j0 + jj)] = v[k];
    // stage for mirror
#pragma unroll
    for (int k = 0; k < 2; ++k) tile[r0 + k][jj] = v[k];
    __syncthreads();
    // mirror (lower): row j0+q, col i0+jj = tile[jj][q] — 64B runs
#pragma unroll
    for (int k = 0; k < 2; ++k) {
      const int q = r0 + k;
      out[(size_t)(j0 + q) * N + (i0 + jj)] = tile[jj][q];
    }
  } else {
#pragma unroll
    for (int k = 0; k < 2; ++k) {
      const int r = r0 + k;
      if (jj >= r) out[(size_t)(i0 + r) * N + (j0 + jj)] = v[k];
      tile[r][jj] = v[k];
    }
    __syncthreads();
#pragma unroll
    for (int k = 0; k < 2; ++k) {
      const int q = r0 + k;
      if (q > jj) out[(size_t)(j0 + q) * N + (i0 + jj)] = tile[jj][q];
    }
  }
}

extern "C" void kernel_launch(void* const* d_in, const int* in_sizes, int n_in,
                              void* d_out, int out_size, void* d_ws, size_t ws_size,
                              hipStream_t stream) {
  const float* muX = (const float*)d_in[0];
  const float* ls  = (const float*)d_in[1];
  float* out = (float*)d_out;
  float2* msT2 = (float2*)d_ws;  // [D/2][N] packed (mu,sig,mu,sig) = 2 MB
  prep3<<<dim3(N / RI), dim3(256), 0, stream>>>(muX, ls, msT2);
  const int ntiles = (N / 16) * (N / 16 + 1) / 2;  // 2080
  pair_kernel<<<dim3(ntiles), dim3(128), 0, stream>>>((const float4*)msT2,
                                                      out);
}